// Round 6
// baseline (216.878 us; speedup 1.0000x reference)
//
#include <hip/hip_runtime.h>
#include <math.h>

#define N 256
#define G 4
#define BLK 1024
#define M 16          // Krylov dim per sweep (fixed schedule + breakdown freeze)
#define NSWEEP 2
#define UTS 280       // uT row stride in halfs
#define U32S 260      // fp32 u row stride

typedef _Float16 half8v __attribute__((ext_vector_type(8)));
typedef float float4v __attribute__((ext_vector_type(4)));

// ---- LDS arena (bytes), all offsets 16-aligned ----
#define OFF_V     0          // (M+1)*N*G fp32 = 69632  : V[(i*N+c)*G+g]
#define OFF_UT    69632      // 16*UTS*2 = 8960 (rows 4..15 garbage-read by B-frags)
#define OFF_U32   78592      // G*U32S*4 = 4160
#define OFF_ZTW   82752      // 16*64*4 = 4096
#define OFF_PART  86848      // (M+2)*16*G*4 = 4608
#define OFF_H     91456      // (M+1)*M*G*4 = 4352 : H[(i*M+j)*G+g]
#define OFF_CS    95808      // G*M*4 = 256
#define OFF_SN    96064      // 256
#define OFF_GG    96320      // G*(M+1)*4 = 272
#define OFF_YY    96592      // 256
#define OFF_ZN    96848      // 16
#define OFF_BETA  96864      // 16
#define ARENA_SZ  96880

__device__ __forceinline__ void red_write(float p, int slot, float* part, int tid) {
    p += __shfl_down(p, 4);
    p += __shfl_down(p, 8);
    p += __shfl_down(p, 16);
    p += __shfl_down(p, 32);
    if ((tid & 63) < 4) part[(slot * 16 + (tid >> 6)) * G + (tid & 3)] = p;
}

// B-fragment read: lane provides B[k=32t+8mq+j][n=mn].
#define LD_FRAG(base, t) (*(const half8v*)((base) + mn * UTS + 32 * (t) + 8 * mq))

__global__ __launch_bounds__(BLK, 4) void cayley_v6(const float* __restrict__ x_all,
                                                    const float* __restrict__ P,
                                                    const float* __restrict__ v_in,
                                                    float* __restrict__ out, int batch) {
    __shared__ __align__(16) char arena[ARENA_SZ];
    float* sV      = (float*)(arena + OFF_V);
    _Float16* uT   = (_Float16*)(arena + OFF_UT);
    float* sU32    = (float*)(arena + OFF_U32);
    float* zTw     = (float*)(arena + OFF_ZTW);
    float* sPart   = (float*)(arena + OFF_PART);
    float* sH      = (float*)(arena + OFF_H);
    float* sCs     = (float*)(arena + OFF_CS);
    float* sSn     = (float*)(arena + OFF_SN);
    float* sGg     = (float*)(arena + OFF_GG);
    float* sYy     = (float*)(arena + OFF_YY);
    float* sZn     = (float*)(arena + OFF_ZN);
    float* sBeta   = (float*)(arena + OFF_BETA);

    const int tid = threadIdx.x;
    const int lane = tid & 63, wv = tid >> 6;
    const int mn = lane & 15, mq = lane >> 4;        // MFMA fragment coords
    const int c = tid >> 2, g = tid & 3;             // solver coords
    const int coff = lane >> 2;                      // c & 15
    const int sys = blockIdx.x * G + g;
    const bool alive = sys < batch;

    // ---- preamble: S = P - P^T rows [16wv,16wv+16) as f16 A-fragments in regs ----
    half8v Shi[8];
    {
        const int r = 16 * wv + mn;
#pragma unroll
        for (int t = 0; t < 8; ++t) {
            const int k0 = 32 * t + 8 * mq;
            float4v pa = *(const float4v*)(P + r * N + k0);
            float4v pb = *(const float4v*)(P + r * N + k0 + 4);
            float sv[8];
            sv[0] = pa.x; sv[1] = pa.y; sv[2] = pa.z; sv[3] = pa.w;
            sv[4] = pb.x; sv[5] = pb.y; sv[6] = pb.z; sv[7] = pb.w;
            half8v hi;
#pragma unroll
            for (int jj = 0; jj < 8; ++jj)
                hi[jj] = (_Float16)(sv[jj] - P[(k0 + jj) * N + r]);
            Shi[t] = hi;
        }
    }

    const float x_own = alive ? x_all[sys * N + c] : 0.f;
    const float v_own = v_in[c];
    float wsol = 0.f;

    for (int sw = 0; sw < NSWEEP; ++sw) {
        // ---- fp32 residual r = v - w - S(x.*w); S streamed from L2-resident P ----
        float r;
        if (sw == 0) {
            r = alive ? v_own : 0.f;
        } else {
            sU32[g * U32S + c] = x_own * wsol;
            __syncthreads();
            const float* urow = &sU32[g * U32S];
            float ac0 = 0.f, ac1 = 0.f, ac2 = 0.f, ac3 = 0.f;
#pragma unroll 4
            for (int j4 = 0; j4 < N; j4 += 4) {
                float4v pa = *(const float4v*)&P[c * N + j4];
                float q0 = P[(j4 + 0) * N + c];
                float q1 = P[(j4 + 1) * N + c];
                float q2 = P[(j4 + 2) * N + c];
                float q3 = P[(j4 + 3) * N + c];
                float4v uu = *(const float4v*)&urow[j4];
                ac0 = fmaf(pa.x - q0, uu.x, ac0);
                ac1 = fmaf(pa.y - q1, uu.y, ac1);
                ac2 = fmaf(pa.z - q2, uu.z, ac2);
                ac3 = fmaf(pa.w - q3, uu.w, ac3);
            }
            r = alive ? (v_own - wsol - ((ac0 + ac1) + (ac2 + ac3))) : 0.f;
        }

        red_write(r * r, 0, sPart, tid);
        __syncthreads();
        if (tid < 4) {
            float s = 0.f;
#pragma unroll
            for (int q = 0; q < 16; ++q) s += sPart[q * G + tid];
            sBeta[tid] = sqrtf(s);
        }
        __syncthreads();

        const float beta = sBeta[g];
        const float ib = (beta > 1e-30f) ? 1.f / beta : 0.f;
        float qcur = r * ib;
        sV[c * G + g] = qcur;                         // V_0
        uT[g * UTS + c] = (_Float16)(x_own * qcur);

        // ---- inner GMRES(M), fixed M iterations, 3 barriers/iter ----
        for (int j = 0; j < M; ++j) {
            __syncthreads();                                          // A
            // z = q + S (x.*q) via MFMA (2 accumulators for ILP)
            float4v acc0 = {0.f, 0.f, 0.f, 0.f};
            float4v acc1 = {0.f, 0.f, 0.f, 0.f};
#pragma unroll
            for (int t = 0; t < 4; ++t) {
                acc0 = __builtin_amdgcn_mfma_f32_16x16x32_f16(Shi[t], LD_FRAG(uT, t), acc0, 0, 0, 0);
                acc1 = __builtin_amdgcn_mfma_f32_16x16x32_f16(Shi[t + 4], LD_FRAG(uT, t + 4), acc1, 0, 0, 0);
            }
            float4v acc = acc0 + acc1;
            if (mn < 4) *(float4v*)(zTw + wv * 64 + mn * 16 + mq * 4) = acc;
            float z = qcur + zTw[wv * 64 + g * 16 + coff];            // intra-wave

            // fused dots h_i = V_i^T z (i<=j, V from LDS) and ||z||^2 at slot j+1
#pragma unroll
            for (int i = 0; i < M; ++i)
                if (i <= j) red_write(sV[(i * N + c) * G + g] * z, i, sPart, tid);
            red_write(z * z, j + 1, sPart, tid);
            __syncthreads();                                          // C
            if (tid < 4 * (j + 2)) {
                const int i = tid >> 2, gq = tid & 3;
                float s = 0.f;
#pragma unroll
                for (int q = 0; q < 16; ++q) s += sPart[(i * 16 + q) * G + gq];
                if (i <= j) sH[(i * M + j) * G + gq] = s;
                else sZn[gq] = s;
            }
            __syncthreads();                                          // D

            // CGS1 update + Pythagorean norm with happy-breakdown freeze:
            // if the new orthogonal component is < 2e-3 rel (below the f16
            // matvec floor), truncate the Krylov space: hj1=0, vnew=0.  Zero
            // vectors self-perpetuate harmlessly and the QR/backsub guards
            // yield y=0 for the frozen columns (textbook happy breakdown).
            float h2 = 0.f;
#pragma unroll
            for (int i = 0; i < M; ++i)
                if (i <= j) {
                    float hi = sH[(i * M + j) * G + g];
                    z = fmaf(-hi, sV[(i * N + c) * G + g], z);
                    h2 = fmaf(hi, hi, h2);
                }
            const float zn2 = sZn[g];           // g-uniform
            const float s2raw = zn2 - h2;       // g-uniform (identical arithmetic)
            const bool frozen = (s2raw <= 4e-6f * zn2);
            const float hj1 = frozen ? 0.f : sqrtf(s2raw);
            const float vscale = frozen ? 0.f : 1.f / hj1;
            const float vnew = z * vscale;
            sV[((j + 1) * N + c) * G + g] = vnew;
            qcur = vnew;
            uT[g * UTS + c] = (_Float16)(x_own * vnew);
            if (tid < 4) sH[((j + 1) * M + j) * G + tid] = hj1;       // lane g==tid
        }
        __syncthreads();   // last column + hj1 writes visible

        // ---- Hessenberg LSQ: Givens QR + backsub, once per sweep (4 lanes) ----
        if (tid < 4) {
            const int gq = tid;
            float gcur = sBeta[gq];
            for (int j = 0; j < M; ++j) {
                float col[M + 1];
#pragma unroll
                for (int i = 0; i < M + 1; ++i)
                    if (i <= j + 1) col[i] = sH[(i * M + j) * G + gq];
#pragma unroll
                for (int i = 0; i < M - 1; ++i)
                    if (i < j) {
                        float cc = sCs[gq * M + i], ss = sSn[gq * M + i];
                        float t0 = fmaf(cc, col[i], ss * col[i + 1]);
                        col[i + 1] = fmaf(-ss, col[i], cc * col[i + 1]);
                        col[i] = t0;
                    }
                float aj = col[j], bj = col[j + 1];
                float rr = sqrtf(fmaf(aj, aj, bj * bj));
                float cc = 1.f, ss = 0.f;
                if (rr > 1e-30f) { cc = aj / rr; ss = bj / rr; }
                sCs[gq * M + j] = cc;
                sSn[gq * M + j] = ss;
#pragma unroll
                for (int i = 0; i < M; ++i)
                    if (i < j) sH[(i * M + j) * G + gq] = col[i];
                sH[(j * M + j) * G + gq] = rr;
                sGg[gq * (M + 1) + j] = cc * gcur;
                gcur = -ss * gcur;
            }
            for (int i = M - 1; i >= 0; --i) {
                float s = sGg[gq * (M + 1) + i];
                for (int l = i + 1; l < M; ++l)
                    s = fmaf(-sH[(i * M + l) * G + gq], sYy[gq * M + l], s);
                float d = sH[(i * M + i) * G + gq];
                sYy[gq * M + i] = (fabsf(d) > 1e-30f) ? s / d : 0.f;
            }
        }
        __syncthreads();   // y visible

#pragma unroll
        for (int i = 0; i < M; ++i)
            wsol = fmaf(sYy[g * M + i], sV[(i * N + c) * G + g], wsol);
        __syncthreads();   // sV reads done before next sweep overwrites
    }

    if (alive) out[sys * N + c] = 2.f * wsol - v_own;
}

extern "C" void kernel_launch(void* const* d_in, const int* in_sizes, int n_in,
                              void* d_out, int out_size, void* d_ws, size_t ws_size,
                              hipStream_t stream) {
    const float* x = (const float*)d_in[0];   // (B*T, 256)
    const float* P = (const float*)d_in[1];   // skew_param (256,256)
    const float* v = (const float*)d_in[2];   // (1,256)
    float* out = (float*)d_out;
    const int batch = in_sizes[0] / N;        // B*T

    const int nblk = (batch + G - 1) / G;
    hipLaunchKernelGGL(cayley_v6, dim3(nblk), dim3(BLK), 0, stream, x, P, v, out, batch);
}

// Round 7
// 191.810 us; speedup vs baseline: 1.1307x; 1.1307x over previous
//
#include <hip/hip_runtime.h>
#include <math.h>

#define N 256
#define G 4
#define BLK 1024
#define M 13          // Krylov dim per sweep (fixed schedule + breakdown freeze)
#define NSWEEP 2
#define VS 264        // f32 V/zT row stride in words (1056 B, 16B-aligned, bank-staggered)
#define UTS 280       // uT row stride in halfs

typedef _Float16 half8v __attribute__((ext_vector_type(8)));
typedef float float4v __attribute__((ext_vector_type(4)));

// ---- LDS arena (bytes), 16-aligned ----
#define OFF_V     0          // (M+1)*G*VS*4 = 59136 : V[(i*G+g)*VS + c]
#define OFF_ZT    59136      // G*VS*4 = 4224 : z (and outer-residual u) [g*VS+c]
#define OFF_UT    63360      // 16*UTS*2 = 8960 (rows 4..15 garbage-read by B-frags)
#define OFF_ZTW   72320      // 16*64*4 = 4096 : MFMA out staging
#define OFF_H     76416      // (M+1)*M*G*4 = 2912 : H[(i*M+j)*G+g]
#define OFF_R     79328      // M*M*G*4 = 2704
#define OFF_YY    82032      // M*G*4 = 208
#define OFF_PART  82240      // 16*G*4 = 256
#define OFF_ZN    82496      // 16
#define OFF_BETA  82512      // 16
#define ARENA_SZ  82528

__device__ __forceinline__ float wsum(float p) {   // full-wave sum, result in all lanes
    p += __shfl_xor(p, 32); p += __shfl_xor(p, 16); p += __shfl_xor(p, 8);
    p += __shfl_xor(p, 4);  p += __shfl_xor(p, 2);  p += __shfl_xor(p, 1);
    return p;
}

__device__ __forceinline__ void red_write(float p, float* part, int tid) {
    p += __shfl_down(p, 4);
    p += __shfl_down(p, 8);
    p += __shfl_down(p, 16);
    p += __shfl_down(p, 32);
    if ((tid & 63) < 4) part[(tid >> 6) * G + (tid & 3)] = p;
}

// B-fragment read: lane provides B[k=32t+8mq+j][n=mn].
#define LD_FRAG(base, t) (*(const half8v*)((base) + mn * UTS + 32 * (t) + 8 * mq))

__global__ __launch_bounds__(BLK, 4) void cayley_v7(const float* __restrict__ x_all,
                                                    const float* __restrict__ P,
                                                    const float* __restrict__ v_in,
                                                    float* __restrict__ out, int batch) {
    __shared__ __align__(16) char arena[ARENA_SZ];
    float* sV      = (float*)(arena + OFF_V);
    float* sZT     = (float*)(arena + OFF_ZT);
    _Float16* uT   = (_Float16*)(arena + OFF_UT);
    float* zTw     = (float*)(arena + OFF_ZTW);
    float* sH      = (float*)(arena + OFF_H);
    float* sR      = (float*)(arena + OFF_R);
    float* sYy     = (float*)(arena + OFF_YY);
    float* sPart   = (float*)(arena + OFF_PART);
    float* sZn     = (float*)(arena + OFF_ZN);
    float* sBeta   = (float*)(arena + OFF_BETA);

    const int tid = threadIdx.x;
    const int lane = tid & 63, wv = tid >> 6;
    const int mn = lane & 15, mq = lane >> 4;        // MFMA fragment coords
    const int c = tid >> 2, g = tid & 3;             // solver coords
    const int coff = lane >> 2;                      // c & 15
    const int sys = blockIdx.x * G + g;
    const bool alive = sys < batch;

    // ---- preamble: S = P - P^T rows [16wv,16wv+16) as f16 A-fragments in regs ----
    half8v Shi[8];
    {
        const int r = 16 * wv + mn;
#pragma unroll
        for (int t = 0; t < 8; ++t) {
            const int k0 = 32 * t + 8 * mq;
            float4v pa = *(const float4v*)(P + r * N + k0);
            float4v pb = *(const float4v*)(P + r * N + k0 + 4);
            float sv[8];
            sv[0] = pa.x; sv[1] = pa.y; sv[2] = pa.z; sv[3] = pa.w;
            sv[4] = pb.x; sv[5] = pb.y; sv[6] = pb.z; sv[7] = pb.w;
            half8v hi;
#pragma unroll
            for (int jj = 0; jj < 8; ++jj)
                hi[jj] = (_Float16)(sv[jj] - P[(k0 + jj) * N + r]);
            Shi[t] = hi;
        }
    }

    const float x_own = alive ? x_all[sys * N + c] : 0.f;
    const float v_own = v_in[c];
    float wsol = 0.f;

    for (int sw = 0; sw < NSWEEP; ++sw) {
        // ---- fp32 residual r = v - w - S(x.*w); S streamed from L2-resident P ----
        float r;
        if (sw == 0) {
            r = alive ? v_own : 0.f;
        } else {
            sZT[g * VS + c] = x_own * wsol;
            __syncthreads();
            const float* urow = sZT + g * VS;
            float ac0 = 0.f, ac1 = 0.f, ac2 = 0.f, ac3 = 0.f;
#pragma unroll 4
            for (int j4 = 0; j4 < N; j4 += 4) {
                float4v pa = *(const float4v*)&P[c * N + j4];
                float q0 = P[(j4 + 0) * N + c];
                float q1 = P[(j4 + 1) * N + c];
                float q2 = P[(j4 + 2) * N + c];
                float q3 = P[(j4 + 3) * N + c];
                float4v uu = *(const float4v*)&urow[j4];
                ac0 = fmaf(pa.x - q0, uu.x, ac0);
                ac1 = fmaf(pa.y - q1, uu.y, ac1);
                ac2 = fmaf(pa.z - q2, uu.z, ac2);
                ac3 = fmaf(pa.w - q3, uu.w, ac3);
            }
            r = alive ? (v_own - wsol - ((ac0 + ac1) + (ac2 + ac3))) : 0.f;
            __syncthreads();   // sZT reads done before iter loop reuses it
        }

        red_write(r * r, sPart, tid);
        __syncthreads();
        if (tid < 4) {
            float s = 0.f;
#pragma unroll
            for (int q = 0; q < 16; ++q) s += sPart[q * G + tid];
            sBeta[tid] = sqrtf(s);
        }
        __syncthreads();

        const float beta = sBeta[g];
        const float ib = (beta > 1e-30f) ? 1.f / beta : 0.f;
        float qcur = r * ib;
        sV[g * VS + c] = qcur;                        // V_0
        uT[g * UTS + c] = (_Float16)(x_own * qcur);

        // ---- inner GMRES(M), fixed M iterations, 3 barriers/iter ----
        for (int j = 0; j < M; ++j) {
            __syncthreads();                                          // A
            // z = q + S (x.*q) via MFMA
            float4v acc0 = {0.f, 0.f, 0.f, 0.f};
            float4v acc1 = {0.f, 0.f, 0.f, 0.f};
#pragma unroll
            for (int t = 0; t < 4; ++t) {
                acc0 = __builtin_amdgcn_mfma_f32_16x16x32_f16(Shi[t], LD_FRAG(uT, t), acc0, 0, 0, 0);
                acc1 = __builtin_amdgcn_mfma_f32_16x16x32_f16(Shi[t + 4], LD_FRAG(uT, t + 4), acc1, 0, 0, 0);
            }
            float4v acc = acc0 + acc1;
            if (mn < 4) *(float4v*)(zTw + wv * 64 + mn * 16 + mq * 4) = acc;
            const float z = qcur + zTw[wv * 64 + g * 16 + coff];      // intra-wave
            sZT[g * VS + c] = z;
            __syncthreads();                                          // B

            // dots: wave i computes slot i (V_i . z for i<=j; ||z||^2 for i=j+1)
            if (wv <= j + 1) {
                const int gq = lane >> 4, q = lane & 15;
                const float* vsrc = (wv <= j) ? (sV + (wv * G + gq) * VS + 16 * q)
                                              : (sZT + gq * VS + 16 * q);
                const float* zsrc = sZT + gq * VS + 16 * q;
                float4v a0 = *(const float4v*)(vsrc);
                float4v a1 = *(const float4v*)(vsrc + 4);
                float4v a2 = *(const float4v*)(vsrc + 8);
                float4v a3 = *(const float4v*)(vsrc + 12);
                float4v b0 = *(const float4v*)(zsrc);
                float4v b1 = *(const float4v*)(zsrc + 4);
                float4v b2 = *(const float4v*)(zsrc + 8);
                float4v b3 = *(const float4v*)(zsrc + 12);
                float p = a0.x * b0.x;
                p = fmaf(a0.y, b0.y, p); p = fmaf(a0.z, b0.z, p); p = fmaf(a0.w, b0.w, p);
                p = fmaf(a1.x, b1.x, p); p = fmaf(a1.y, b1.y, p);
                p = fmaf(a1.z, b1.z, p); p = fmaf(a1.w, b1.w, p);
                p = fmaf(a2.x, b2.x, p); p = fmaf(a2.y, b2.y, p);
                p = fmaf(a2.z, b2.z, p); p = fmaf(a2.w, b2.w, p);
                p = fmaf(a3.x, b3.x, p); p = fmaf(a3.y, b3.y, p);
                p = fmaf(a3.z, b3.z, p); p = fmaf(a3.w, b3.w, p);
                p += __shfl_xor(p, 1); p += __shfl_xor(p, 2);
                p += __shfl_xor(p, 4); p += __shfl_xor(p, 8);
                if (q == 0) {
                    if (wv <= j) sH[(wv * M + j) * G + gq] = p;
                    else sZn[gq] = p;
                }
            }
            __syncthreads();                                          // C

            // CGS1 update + Pythagorean norm + happy-breakdown freeze
            float h2 = 0.f, zo = z;
#pragma unroll
            for (int i = 0; i < M; ++i)
                if (i <= j) {
                    float hi = sH[(i * M + j) * G + g];
                    zo = fmaf(-hi, sV[(i * G + g) * VS + c], zo);
                    h2 = fmaf(hi, hi, h2);
                }
            const float zn2 = sZn[g];            // g-uniform
            const float diff = zn2 - h2;         // g-uniform
            const bool frozen = (diff <= 4e-6f * zn2);
            const float hj1 = frozen ? 0.f : sqrtf(diff);
            const float vnew = frozen ? 0.f : zo * (1.f / hj1);
            sV[((j + 1) * G + g) * VS + c] = vnew;
            qcur = vnew;
            uT[g * UTS + c] = (_Float16)(x_own * vnew);
            if (tid < 4) sH[((j + 1) * M + j) * G + tid] = hj1;       // g==tid
        }
        __syncthreads();   // H complete

        // ---- LSQ min||beta*e1 - H y||: wave-parallel MGS-QR + backsub.
        // Wave gq<4 handles system gq; rows of H on lanes. No private arrays.
        if (wv < 4) {
            const int gq = wv;
            const int rr_ = lane;
            const float betag = sBeta[gq];
            for (int jj = 0; jj < M; ++jj) {
                float hv = (rr_ <= jj + 1) ? sH[(rr_ * M + jj) * G + gq] : 0.f;
                for (int i = 0; i < jj; ++i) {
                    float qv = (rr_ <= i + 1) ? sH[(rr_ * M + i) * G + gq] : 0.f;
                    float d = wsum(qv * hv);
                    hv = fmaf(-d, qv, hv);
                    if (rr_ == 0) sR[(i * M + jj) * G + gq] = d;
                }
                float nn = wsum(hv * hv);
                float rjj = sqrtf(nn);
                float qn = (rjj > 1e-30f) ? hv * (1.f / rjj) : 0.f;
                if (rr_ <= jj + 1) sH[(rr_ * M + jj) * G + gq] = qn;  // col jj := q_jj
                float q0 = __shfl(qn, 0);
                if (rr_ == 0) {
                    sR[(jj * M + jj) * G + gq] = rjj;
                    sYy[jj * G + gq] = betag * q0;                    // rhs_jj
                }
            }
            float yl = 0.f;                                           // lane rr_ holds y_rr_
            for (int i = M - 1; i >= 0; --i) {
                float Ril = (rr_ > i && rr_ < M) ? sR[(i * M + rr_) * G + gq] : 0.f;
                float s = wsum(Ril * yl);
                float rhs = sYy[i * G + gq];
                float dii = sR[(i * M + i) * G + gq];
                float yi = (fabsf(dii) > 1e-30f) ? (rhs - s) / dii : 0.f;
                if (rr_ == i) yl = yi;
                if (rr_ == 0) sYy[i * G + gq] = yi;
            }
        }
        __syncthreads();   // y visible

#pragma unroll
        for (int i = 0; i < M; ++i)
            wsol = fmaf(sYy[i * G + g], sV[(i * G + g) * VS + c], wsol);
        __syncthreads();   // sV/sYy reads done before next sweep overwrites
    }

    if (alive) out[sys * N + c] = 2.f * wsol - v_own;
}

extern "C" void kernel_launch(void* const* d_in, const int* in_sizes, int n_in,
                              void* d_out, int out_size, void* d_ws, size_t ws_size,
                              hipStream_t stream) {
    const float* x = (const float*)d_in[0];   // (B*T, 256)
    const float* P = (const float*)d_in[1];   // skew_param (256,256)
    const float* v = (const float*)d_in[2];   // (1,256)
    float* out = (float*)d_out;
    const int batch = in_sizes[0] / N;        // B*T

    const int nblk = (batch + G - 1) / G;
    hipLaunchKernelGGL(cayley_v7, dim3(nblk), dim3(BLK), 0, stream, x, P, v, out, batch);
}

// Round 8
// 163.974 us; speedup vs baseline: 1.3226x; 1.1698x over previous
//
#include <hip/hip_runtime.h>
#include <math.h>

#define N 256
#define G 4
#define BLK 1024
#define M1 13         // Krylov dim, sweep 1 (fixed schedule + breakdown freeze)
#define M2 10         // Krylov dim, sweep 2
#define VS 268        // f32 V/z row stride: %32==12 -> b128 dot reads cover all start-banks
#define UTS 280       // f16 uT row stride

typedef _Float16 half8v __attribute__((ext_vector_type(8)));
typedef float float4v __attribute__((ext_vector_type(4)));

// ---- LDS arena (bytes), 16-aligned ----
#define OFF_V     0          // (M1+1)*G*VS*4 = 60032 : V[(i*G+g)*VS + c]
#define OFF_ZT    60032      // G*VS*4 = 4288 : z scratch [g*VS+c]
#define OFF_UT    64320      // 16*UTS*2 = 8960 (rows 4..15 garbage-read by B-frags)
#define OFF_ZTW   73280      // 16*64*4 = 4096 : MFMA out staging
#define OFF_H     77376      // (M1+1)*M1*G*4 = 2912 : H[(i*M1+j)*G+g]
#define OFF_R     80288      // M1*M1*G*4 = 2704
#define OFF_YY    82992      // M1*G*4 = 208
#define OFF_PART  83200      // 16*G*4 = 256
#define OFF_ZN    83456      // 16
#define OFF_BETA  83472      // 16
#define ARENA_SZ  83488

__device__ __forceinline__ float wsum(float p) {   // full-wave sum, result in all lanes
    p += __shfl_xor(p, 32); p += __shfl_xor(p, 16); p += __shfl_xor(p, 8);
    p += __shfl_xor(p, 4);  p += __shfl_xor(p, 2);  p += __shfl_xor(p, 1);
    return p;
}

__device__ __forceinline__ void red_write(float p, float* part, int tid) {
    p += __shfl_down(p, 4);
    p += __shfl_down(p, 8);
    p += __shfl_down(p, 16);
    p += __shfl_down(p, 32);
    if ((tid & 63) < 4) part[(tid >> 6) * G + (tid & 3)] = p;
}

// B-fragment read: lane provides B[k=32t+8mq+j][n=mn].
#define LD_FRAG(base, t) (*(const half8v*)((base) + mn * UTS + 32 * (t) + 8 * mq))

// z = S (x.*q): f16 MFMA matvec, result for this thread's (c,g) via intra-wave staging.
#define MATVEC(dst) do {                                                               \
    float4v acc0 = {0.f, 0.f, 0.f, 0.f};                                               \
    float4v acc1 = {0.f, 0.f, 0.f, 0.f};                                               \
    _Pragma("unroll")                                                                  \
    for (int t = 0; t < 4; ++t) {                                                      \
        acc0 = __builtin_amdgcn_mfma_f32_16x16x32_f16(Shi[t], LD_FRAG(uT, t), acc0, 0, 0, 0);        \
        acc1 = __builtin_amdgcn_mfma_f32_16x16x32_f16(Shi[t + 4], LD_FRAG(uT, t + 4), acc1, 0, 0, 0);\
    }                                                                                  \
    float4v accs = acc0 + acc1;                                                        \
    if (mn < 4) *(float4v*)(zTw + wv * 64 + mn * 16 + mq * 4) = accs;                  \
    dst = zTw[wv * 64 + g * 16 + coff];                                                \
} while (0)

__global__ __launch_bounds__(BLK, 4) void cayley_v8(const float* __restrict__ x_all,
                                                    const float* __restrict__ P,
                                                    const float* __restrict__ v_in,
                                                    float* __restrict__ out, int batch) {
    __shared__ __align__(16) char arena[ARENA_SZ];
    float* sV      = (float*)(arena + OFF_V);
    float* sZT     = (float*)(arena + OFF_ZT);
    _Float16* uT   = (_Float16*)(arena + OFF_UT);
    float* zTw     = (float*)(arena + OFF_ZTW);
    float* sH      = (float*)(arena + OFF_H);
    float* sR      = (float*)(arena + OFF_R);
    float* sYy     = (float*)(arena + OFF_YY);
    float* sPart   = (float*)(arena + OFF_PART);
    float* sZn     = (float*)(arena + OFF_ZN);
    float* sBeta   = (float*)(arena + OFF_BETA);

    const int tid = threadIdx.x;
    const int lane = tid & 63, wv = tid >> 6;
    const int mn = lane & 15, mq = lane >> 4;        // MFMA fragment coords
    const int c = tid >> 2, g = tid & 3;             // solver coords
    const int coff = lane >> 2;                      // c & 15
    const int sys = blockIdx.x * G + g;
    const bool alive = sys < batch;

    // ---- preamble: S = P - P^T rows [16wv,16wv+16) as f16 A-fragments in regs ----
    half8v Shi[8];
    {
        const int r = 16 * wv + mn;
#pragma unroll
        for (int t = 0; t < 8; ++t) {
            const int k0 = 32 * t + 8 * mq;
            float4v pa = *(const float4v*)(P + r * N + k0);
            float4v pb = *(const float4v*)(P + r * N + k0 + 4);
            half8v hi;
            hi[0] = (_Float16)(pa.x - P[(k0 + 0) * N + r]);
            hi[1] = (_Float16)(pa.y - P[(k0 + 1) * N + r]);
            hi[2] = (_Float16)(pa.z - P[(k0 + 2) * N + r]);
            hi[3] = (_Float16)(pa.w - P[(k0 + 3) * N + r]);
            hi[4] = (_Float16)(pb.x - P[(k0 + 4) * N + r]);
            hi[5] = (_Float16)(pb.y - P[(k0 + 5) * N + r]);
            hi[6] = (_Float16)(pb.z - P[(k0 + 6) * N + r]);
            hi[7] = (_Float16)(pb.w - P[(k0 + 7) * N + r]);
            Shi[t] = hi;
        }
    }

    const float x_own = alive ? x_all[sys * N + c] : 0.f;
    const float v_own = v_in[c];
    float wsol = 0.f;

    for (int sw = 0; sw < 2; ++sw) {
        const int Msw = sw ? M2 : M1;

        // ---- residual r = v - w - S(x.*w) via the same f16 MFMA operator ----
        float r;
        if (sw == 0) {
            r = alive ? v_own : 0.f;
        } else {
            uT[g * UTS + c] = (_Float16)(x_own * wsol);
            __syncthreads();
            float zm;
            MATVEC(zm);
            r = alive ? (v_own - wsol - zm) : 0.f;
        }

        red_write(r * r, sPart, tid);
        __syncthreads();
        if (tid < 4) {
            float s = 0.f;
#pragma unroll
            for (int q = 0; q < 16; ++q) s += sPart[q * G + tid];
            sBeta[tid] = sqrtf(s);
        }
        __syncthreads();

        const float beta = sBeta[g];
        float qcur = (beta > 1e-30f) ? r / beta : 0.f;
        sV[g * VS + c] = qcur;                        // V_0
        uT[g * UTS + c] = (_Float16)(x_own * qcur);

        // ---- inner GMRES(Msw), fixed schedule, 3 barriers/iter ----
        for (int j = 0; j < Msw; ++j) {
            __syncthreads();                                          // A: uT ready
            float zm;
            MATVEC(zm);
            const float z = qcur + zm;
            sZT[g * VS + c] = z;
            __syncthreads();                                          // B

            // dots: wave i computes slot i (V_i . z for i<=j; ||z||^2 at i=j+1),
            // 8 dwords per step to cap register pressure.
            if (wv <= j + 1) {
                const int gq = lane >> 4, q = lane & 15;
                const float* vsrc = (wv <= j) ? (sV + (wv * G + gq) * VS + 16 * q)
                                              : (sZT + gq * VS + 16 * q);
                const float* zsrc = sZT + gq * VS + 16 * q;
                float p;
                {
                    float4v a0 = *(const float4v*)(vsrc);
                    float4v b0 = *(const float4v*)(zsrc);
                    float4v a1 = *(const float4v*)(vsrc + 4);
                    float4v b1 = *(const float4v*)(zsrc + 4);
                    p = a0.x * b0.x;
                    p = fmaf(a0.y, b0.y, p); p = fmaf(a0.z, b0.z, p); p = fmaf(a0.w, b0.w, p);
                    p = fmaf(a1.x, b1.x, p); p = fmaf(a1.y, b1.y, p);
                    p = fmaf(a1.z, b1.z, p); p = fmaf(a1.w, b1.w, p);
                }
                {
                    float4v a0 = *(const float4v*)(vsrc + 8);
                    float4v b0 = *(const float4v*)(zsrc + 8);
                    float4v a1 = *(const float4v*)(vsrc + 12);
                    float4v b1 = *(const float4v*)(zsrc + 12);
                    p = fmaf(a0.x, b0.x, p); p = fmaf(a0.y, b0.y, p);
                    p = fmaf(a0.z, b0.z, p); p = fmaf(a0.w, b0.w, p);
                    p = fmaf(a1.x, b1.x, p); p = fmaf(a1.y, b1.y, p);
                    p = fmaf(a1.z, b1.z, p); p = fmaf(a1.w, b1.w, p);
                }
                p += __shfl_xor(p, 1); p += __shfl_xor(p, 2);
                p += __shfl_xor(p, 4); p += __shfl_xor(p, 8);
                if (q == 0) {
                    if (wv <= j) sH[(wv * M1 + j) * G + gq] = p;
                    else sZn[gq] = p;
                }
            }
            __syncthreads();                                          // C

            // CGS1 update + Pythagorean norm + happy-breakdown freeze
            float h2 = 0.f, zo = z;
#pragma unroll
            for (int i = 0; i < M1; ++i)
                if (i <= j) {
                    float hi = sH[(i * M1 + j) * G + g];
                    zo = fmaf(-hi, sV[(i * G + g) * VS + c], zo);
                    h2 = fmaf(hi, hi, h2);
                }
            const float zn2 = sZn[g];            // g-uniform
            const float diff = zn2 - h2;         // g-uniform
            const bool frozen = (diff <= 4e-6f * zn2);
            const float hj1 = frozen ? 0.f : sqrtf(diff);
            const float vnew = frozen ? 0.f : zo * (1.f / hj1);
            sV[((j + 1) * G + g) * VS + c] = vnew;
            qcur = vnew;
            uT[g * UTS + c] = (_Float16)(x_own * vnew);
            if (tid < 4) sH[((j + 1) * M1 + j) * G + tid] = hj1;      // g==tid
        }
        __syncthreads();   // H complete

        // ---- LSQ min||beta*e1 - H y||: wave-parallel MGS-QR + backsub (no arrays) ----
        if (wv < 4) {
            const int gq = wv;
            const int rr_ = lane;
            const float betag = sBeta[gq];
            for (int jj = 0; jj < Msw; ++jj) {
                float hv = (rr_ <= jj + 1) ? sH[(rr_ * M1 + jj) * G + gq] : 0.f;
                for (int i = 0; i < jj; ++i) {
                    float qv = (rr_ <= i + 1) ? sH[(rr_ * M1 + i) * G + gq] : 0.f;
                    float d = wsum(qv * hv);
                    hv = fmaf(-d, qv, hv);
                    if (rr_ == 0) sR[(i * M1 + jj) * G + gq] = d;
                }
                float nn = wsum(hv * hv);
                float rjj = sqrtf(nn);
                float qn = (rjj > 1e-30f) ? hv * (1.f / rjj) : 0.f;
                if (rr_ <= jj + 1) sH[(rr_ * M1 + jj) * G + gq] = qn; // col jj := q_jj
                float q0 = __shfl(qn, 0);
                if (rr_ == 0) {
                    sR[(jj * M1 + jj) * G + gq] = rjj;
                    sYy[jj * G + gq] = betag * q0;                    // rhs_jj
                }
            }
            float yl = 0.f;                                           // lane rr_ holds y_rr_
            for (int i = Msw - 1; i >= 0; --i) {
                float Ril = (rr_ > i && rr_ < Msw) ? sR[(i * M1 + rr_) * G + gq] : 0.f;
                float s = wsum(Ril * yl);
                float rhs = sYy[i * G + gq];
                float dii = sR[(i * M1 + i) * G + gq];
                float yi = (fabsf(dii) > 1e-30f) ? (rhs - s) / dii : 0.f;
                if (rr_ == i) yl = yi;
                if (rr_ == 0) sYy[i * G + gq] = yi;
            }
        }
        __syncthreads();   // y visible

        for (int i = 0; i < Msw; ++i)
            wsol = fmaf(sYy[i * G + g], sV[(i * G + g) * VS + c], wsol);
        __syncthreads();   // sV/sYy reads done before next sweep overwrites
    }

    if (alive) out[sys * N + c] = 2.f * wsol - v_own;
}

extern "C" void kernel_launch(void* const* d_in, const int* in_sizes, int n_in,
                              void* d_out, int out_size, void* d_ws, size_t ws_size,
                              hipStream_t stream) {
    const float* x = (const float*)d_in[0];   // (B*T, 256)
    const float* P = (const float*)d_in[1];   // skew_param (256,256)
    const float* v = (const float*)d_in[2];   // (1,256)
    float* out = (float*)d_out;
    const int batch = in_sizes[0] / N;        // B*T

    const int nblk = (batch + G - 1) / G;
    hipLaunchKernelGGL(cayley_v8, dim3(nblk), dim3(BLK), 0, stream, x, P, v, out, batch);
}

// Round 9
// 120.224 us; speedup vs baseline: 1.8039x; 1.3639x over previous
//
#include <hip/hip_runtime.h>
#include <math.h>

#define N 256
#define G 4
#define BLK 1024
#define S1 12         // Krylov steps, sweep 1
#define S2 10         // Krylov steps, sweep 2
#define SP1 13        // S1+1 (array dims)
#define VS 268        // f32 K row stride (words)
#define UTS 280       // f16 uT row stride
#define RIDGE 3e-5f

typedef _Float16 half8v __attribute__((ext_vector_type(8)));
typedef float float4v __attribute__((ext_vector_type(4)));

// ---- LDS arena (bytes), 16-aligned ----
#define OFF_K     0          // SP1*G*VS*4 = 55744 : K[(i*G+g)*VS + c]
#define OFF_UT    55744      // 16*UTS*2 = 8960 (rows 4..15 garbage-read by B-frags)
#define OFF_ZTW   64704      // 16*64*4 = 4096 : MFMA out staging
#define OFF_PART  68800      // 64*4 = 256
#define OFF_NU    69056      // SP1*G*4 = 208
#define OFF_INV   69264      // 208
#define OFF_GRAM  69472      // SP1*SP1*G*4 = 2704 : Gram[(i*SP1+j)*G+g]
#define OFF_L     72176      // S1*S1*G*4 = 2304 : L[(r*S1+k)*G+g]
#define OFF_D     74480      // S1*G*4 = 192
#define ARENA_SZ  74672

__device__ __forceinline__ void red_write(float p, float* part, int tid) {
    p += __shfl_down(p, 4);
    p += __shfl_down(p, 8);
    p += __shfl_down(p, 16);
    p += __shfl_down(p, 32);
    if ((tid & 63) < 4) part[(tid >> 6) * G + (tid & 3)] = p;   // index == lane of a fold-wave
}

// B-fragment read: lane provides B[k=32t+8mq+j][n=mn].
#define LD_FRAG(base, t) (*(const half8v*)((base) + mn * UTS + 32 * (t) + 8 * mq))

// zm = (S (x.*q))[c] for this thread's (c,g); q staged in uT as f16.
#define MATVEC(dst) do {                                                               \
    float4v acc0 = {0.f, 0.f, 0.f, 0.f};                                               \
    float4v acc1 = {0.f, 0.f, 0.f, 0.f};                                               \
    _Pragma("unroll")                                                                  \
    for (int t = 0; t < 4; ++t) {                                                      \
        acc0 = __builtin_amdgcn_mfma_f32_16x16x32_f16(Shi[t], LD_FRAG(uT, t), acc0, 0, 0, 0);        \
        acc1 = __builtin_amdgcn_mfma_f32_16x16x32_f16(Shi[t + 4], LD_FRAG(uT, t + 4), acc1, 0, 0, 0);\
    }                                                                                  \
    float4v accs = acc0 + acc1;                                                        \
    if (mn < 4) *(float4v*)(zTw + wv * 64 + mn * 16 + mq * 4) = accs;                  \
    dst = zTw[wv * 64 + g * 16 + coff];                                                \
} while (0)

// CA-GMRES + fp32 IR: per sweep, build normalized monomial Krylov basis
// k0..ks with s f16-MFMA matvecs (A khat_i = nu_{i+1} khat_{i+1} exactly by
// construction), then ONE Gram pass + per-system ridge-Cholesky LSQ.
__global__ __launch_bounds__(BLK, 4) void cayley_v9(const float* __restrict__ x_all,
                                                    const float* __restrict__ P,
                                                    const float* __restrict__ v_in,
                                                    float* __restrict__ out, int batch) {
    __shared__ __align__(16) char arena[ARENA_SZ];
    float* sK      = (float*)(arena + OFF_K);
    _Float16* uT   = (_Float16*)(arena + OFF_UT);
    float* zTw     = (float*)(arena + OFF_ZTW);
    float* sPart   = (float*)(arena + OFF_PART);
    float* sNu     = (float*)(arena + OFF_NU);
    float* sInv    = (float*)(arena + OFF_INV);
    float* sGram   = (float*)(arena + OFF_GRAM);
    float* sL      = (float*)(arena + OFF_L);
    float* sD      = (float*)(arena + OFF_D);

    const int tid = threadIdx.x;
    const int lane = tid & 63, wv = tid >> 6;
    const int mn = lane & 15, mq = lane >> 4;        // MFMA fragment coords
    const int c = tid >> 2, g = tid & 3;             // solver coords
    const int coff = lane >> 2;                      // c & 15
    const int sys = blockIdx.x * G + g;
    const bool alive = sys < batch;

    // ---- preamble: S = P - P^T rows [16wv,16wv+16) as f16 A-fragments ----
    half8v Shi[8];
    {
        const int r = 16 * wv + mn;
#pragma unroll
        for (int t = 0; t < 8; ++t) {
            const int k0 = 32 * t + 8 * mq;
            float4v pa = *(const float4v*)(P + r * N + k0);
            float4v pb = *(const float4v*)(P + r * N + k0 + 4);
            half8v hi;
            hi[0] = (_Float16)(pa.x - P[(k0 + 0) * N + r]);
            hi[1] = (_Float16)(pa.y - P[(k0 + 1) * N + r]);
            hi[2] = (_Float16)(pa.z - P[(k0 + 2) * N + r]);
            hi[3] = (_Float16)(pa.w - P[(k0 + 3) * N + r]);
            hi[4] = (_Float16)(pb.x - P[(k0 + 4) * N + r]);
            hi[5] = (_Float16)(pb.y - P[(k0 + 5) * N + r]);
            hi[6] = (_Float16)(pb.z - P[(k0 + 6) * N + r]);
            hi[7] = (_Float16)(pb.w - P[(k0 + 7) * N + r]);
            Shi[t] = hi;
        }
    }

    const float x_own = alive ? x_all[sys * N + c] : 0.f;
    const float v_own = v_in[c];
    float wsol = 0.f;

    for (int sw = 0; sw < 2; ++sw) {
        const int s = sw ? S2 : S1;

        // ---- unnormalized K_0 candidate: the fp32 residual (f16 operator) ----
        float z;
        if (sw == 0) {
            z = alive ? v_own : 0.f;
        } else {
            uT[g * UTS + c] = (_Float16)(x_own * wsol);
            __syncthreads();
            float zm;
            MATVEC(zm);
            z = alive ? (v_own - wsol - zm) : 0.f;
        }

        // ---- basis build: normalize, store, matvec; 2 barriers/step ----
        for (int i = 0;; ++i) {
            red_write(z * z, sPart, tid);
            __syncthreads();                               // partials ready
            float pv = sPart[lane];                        // 64 partials = 16 wv x 4 g
            pv += __shfl_xor(pv, 4);
            pv += __shfl_xor(pv, 8);
            pv += __shfl_xor(pv, 16);
            pv += __shfl_xor(pv, 32);                      // class-sum for g = lane&3
            const float inv = (pv > 1e-30f) ? (1.f / sqrtf(pv)) : 0.f;
            const float kq = z * inv;
            sK[(i * G + g) * VS + c] = kq;
            if (wv == 0 && lane < 4) {                     // lane == g
                sNu[i * G + lane] = pv * inv;              // nu_i
                sInv[i * G + lane] = inv;
            }
            if (i == s) break;
            uT[g * UTS + c] = (_Float16)(x_own * kq);
            __syncthreads();                               // uT (and K_i) visible
            float zm;
            MATVEC(zm);
            z = kq + zm;                                   // A khat_i
        }
        __syncthreads();   // K_s, sNu, sInv visible

        // ---- Gram pass: all pairs i<j, distributed over 16 waves ----
        const int NP = s * (s + 1) / 2;
        for (int pp = wv; pp < NP; pp += 16) {
            int i = 0, rem = pp;
            while (rem >= s - i) { rem -= (s - i); ++i; }
            const int j = i + 1 + rem;
            const int gq = lane >> 4, q = lane & 15;
            const float* ka = sK + (i * G + gq) * VS + 16 * q;
            const float* kb = sK + (j * G + gq) * VS + 16 * q;
            float p;
            {
                float4v a0 = *(const float4v*)(ka);
                float4v b0 = *(const float4v*)(kb);
                float4v a1 = *(const float4v*)(ka + 4);
                float4v b1 = *(const float4v*)(kb + 4);
                p = a0.x * b0.x;
                p = fmaf(a0.y, b0.y, p); p = fmaf(a0.z, b0.z, p); p = fmaf(a0.w, b0.w, p);
                p = fmaf(a1.x, b1.x, p); p = fmaf(a1.y, b1.y, p);
                p = fmaf(a1.z, b1.z, p); p = fmaf(a1.w, b1.w, p);
            }
            {
                float4v a0 = *(const float4v*)(ka + 8);
                float4v b0 = *(const float4v*)(kb + 8);
                float4v a1 = *(const float4v*)(ka + 12);
                float4v b1 = *(const float4v*)(kb + 12);
                p = fmaf(a0.x, b0.x, p); p = fmaf(a0.y, b0.y, p);
                p = fmaf(a0.z, b0.z, p); p = fmaf(a0.w, b0.w, p);
                p = fmaf(a1.x, b1.x, p); p = fmaf(a1.y, b1.y, p);
                p = fmaf(a1.z, b1.z, p); p = fmaf(a1.w, b1.w, p);
            }
            p += __shfl_xor(p, 1); p += __shfl_xor(p, 2);
            p += __shfl_xor(p, 4); p += __shfl_xor(p, 8);
            if (q == 0) {
                sGram[(i * SP1 + j) * G + gq] = p;
                sGram[(j * SP1 + i) * G + gq] = p;
            }
        }
        __syncthreads();

        // ---- per-system LSQ: (Gram[1:,1:] + ridge) chat = Gram[1:,0] via
        // wave-parallel Cholesky (wv<4 -> system wv; lanes = rows). ----
        if (wv < 4) {
            const int gq = wv;
            const int rr = lane;
            // Cholesky
            for (int k = 0; k < s; ++k) {
                float a = 0.f;
                if (rr >= k && rr < s) {
                    a = (rr == k) ? (1.f + RIDGE)
                                  : sGram[((rr + 1) * SP1 + (k + 1)) * G + gq];
                    for (int m = 0; m < k; ++m)
                        a = fmaf(-sL[(rr * S1 + m) * G + gq],
                                 sL[(k * S1 + m) * G + gq], a);
                }
                float dk = __shfl(a, k);
                dk = fmaxf(dk, 0.5f * RIDGE);
                const float invd = 1.f / sqrtf(dk);
                if (rr >= k && rr < s) sL[(rr * S1 + k) * G + gq] = a * invd;
            }
            // forward solve L t = rhs  (rhs_r = Gram[r+1][0])
            float trr = 0.f, acc = 0.f;
            const float rhs = (rr < s) ? sGram[((rr + 1) * SP1) * G + gq] : 0.f;
            for (int k = 0; k < s; ++k) {
                const float Lkk = sL[(k * S1 + k) * G + gq];
                float tk = (Lkk > 1e-20f) ? (rhs - acc) / Lkk : 0.f;
                tk = __shfl(tk, k);
                if (rr == k) trr = tk;
                if (rr > k && rr < s)
                    acc = fmaf(sL[(rr * S1 + k) * G + gq], tk, acc);
            }
            // backward solve L^T chat = t
            float crr = 0.f;
            acc = 0.f;
            for (int k = s - 1; k >= 0; --k) {
                const float Lkk = sL[(k * S1 + k) * G + gq];
                float ck = (Lkk > 1e-20f) ? (trr - acc) / Lkk : 0.f;
                ck = __shfl(ck, k);
                if (rr == k) crr = ck;
                if (rr < k) acc = fmaf(sL[(k * S1 + rr) * G + gq], ck, acc);
            }
            // d_i = nu0 * chat_i * inv_{i+1}
            if (rr < s) {
                const float nu0 = sNu[gq];
                const float invn = sInv[(rr + 1) * G + gq];
                sD[rr * G + gq] = nu0 * crr * invn;
            }
        }
        __syncthreads();   // d visible

        // ---- update: w += sum d_i khat_i ----
        for (int i = 0; i < s; ++i)
            wsol = fmaf(sD[i * G + g], sK[(i * G + g) * VS + c], wsol);
        __syncthreads();   // reads done before next sweep overwrites
    }

    if (alive) out[sys * N + c] = 2.f * wsol - v_own;
}

extern "C" void kernel_launch(void* const* d_in, const int* in_sizes, int n_in,
                              void* d_out, int out_size, void* d_ws, size_t ws_size,
                              hipStream_t stream) {
    const float* x = (const float*)d_in[0];   // (B*T, 256)
    const float* P = (const float*)d_in[1];   // skew_param (256,256)
    const float* v = (const float*)d_in[2];   // (1,256)
    float* out = (float*)d_out;
    const int batch = in_sizes[0] / N;        // B*T

    const int nblk = (batch + G - 1) / G;
    hipLaunchKernelGGL(cayley_v9, dim3(nblk), dim3(BLK), 0, stream, x, P, v, out, batch);
}